// Round 11
// baseline (225.906 us; speedup 1.0000x reference)
//
#include <hip/hip_runtime.h>
#include <hip/hip_bf16.h>
#include <hip/hip_fp16.h>

// Self-attention B=8,C=256,H=W=64 -> N=4096, D=32 — all-MFMA pipeline.
// prep -> qkv2 (MFMA, LDS-staged x; R9-exact) -> flash (f16 MFMA, q-split
// 16 rows/wave, kcnt=4) -> merge2 (MFMA wo-proj; R9-exact).
// R10 NaN post-mortem: bisection round — ONLY flash changed vs R9.

typedef _Float16 f16;
typedef f16 f16x8 __attribute__((ext_vector_type(8)));
typedef f16 f16x4 __attribute__((ext_vector_type(4)));
typedef __fp16 h16x2 __attribute__((ext_vector_type(2)));   // cvt_pkrtz return type
typedef float f32x4 __attribute__((ext_vector_type(4)));

#define B_ 8
#define C_ 256
#define N_ 4096
#define D_ 32
#define LOG2E 1.44269504088896f

// native v_exp_f32 computes 2^x; non-volatile so the scheduler can interleave
__device__ __forceinline__ float fexp2(float x) {
    float r;
    asm("v_exp_f32 %0, %1" : "=v"(r) : "v"(x));
    return r;
}

// ---- kernel 0: weight prep (fp32 -> fp16, scale folds) ------------------
__global__ __launch_bounds__(256) void prep_kernel(
    const float* __restrict__ wq, const float* __restrict__ wk,
    const float* __restrict__ wv, const float* __restrict__ wo,
    const float* __restrict__ gamma,
    f16* __restrict__ whq, f16* __restrict__ whk,
    f16* __restrict__ whv, f16* __restrict__ woh)
{
    const int i = blockIdx.x * 256 + threadIdx.x;
    whq[i] = (f16)(wq[i] * LOG2E);      // exp2-domain softmax: s' = s*log2e
    whk[i] = (f16)wk[i];
    whv[i] = (f16)wv[i];
    woh[i] = (f16)(wo[i] * gamma[0]);   // fold gamma into output projection
}

// ---- kernel 1: QKV projection via MFMA, x staged in LDS (R9-exact) ------
__global__ __launch_bounds__(256) void qkv2_kernel(
    const float* __restrict__ x, const f16* __restrict__ whq,
    const f16* __restrict__ whk, const f16* __restrict__ whv,
    f16* __restrict__ Q, f16* __restrict__ K, f16* __restrict__ Vt)
{
    __shared__ f16 xl[256][66];
    const int tid = threadIdx.x;
    const int lane = tid & 63, wid = tid >> 6;
    const int b = blockIdx.y;
    const int n0 = blockIdx.x * 64;
    const int l15 = lane & 15, g = lane >> 4;
    const int nl = wid * 16 + l15;          // n-local in [0,64)
    const int n = n0 + nl;

    // stage: coalesced float4 reads of x[c][n0..n0+63], fp16-convert to LDS
    {
        const float* xb = x + (size_t)b * C_ * N_ + n0;
        const int cb = tid >> 4, ncb = (tid & 15) * 4;
        #pragma unroll
        for (int i = 0; i < 16; ++i) {
            const int c = i * 16 + cb;
            const float4 xv = *(const float4*)(xb + (size_t)c * N_ + ncb);
            *(h16x2*)&xl[c][ncb]     = __builtin_amdgcn_cvt_pkrtz(xv.x, xv.y);
            *(h16x2*)&xl[c][ncb + 2] = __builtin_amdgcn_cvt_pkrtz(xv.z, xv.w);
        }
    }
    __syncthreads();

    f32x4 aq0 = {0.f, 0.f, 0.f, 0.f};
    f32x4 aq1 = aq0, ak0 = aq0, ak1 = aq0, av0 = aq0, av1 = aq0;

    #pragma unroll
    for (int ks = 0; ks < 8; ++ks) {
        const int c0 = ks * 32 + g * 8;
        union { f16x8 v; f16 e[8]; } xf;
        #pragma unroll
        for (int j = 0; j < 8; ++j) xf.e[j] = xl[c0 + j][nl];

        const int woff = l15 * 256 + c0;         // A-frag row d=l15 (+16 for dt1)
        const f16x8 fq0 = *(const f16x8*)(whq + woff);
        const f16x8 fq1 = *(const f16x8*)(whq + woff + 16 * 256);
        const f16x8 fk0 = *(const f16x8*)(whk + woff);
        const f16x8 fk1 = *(const f16x8*)(whk + woff + 16 * 256);
        const f16x8 fv0 = *(const f16x8*)(whv + woff);
        const f16x8 fv1 = *(const f16x8*)(whv + woff + 16 * 256);

        aq0 = __builtin_amdgcn_mfma_f32_16x16x32_f16(fq0, xf.v, aq0, 0, 0, 0);
        aq1 = __builtin_amdgcn_mfma_f32_16x16x32_f16(fq1, xf.v, aq1, 0, 0, 0);
        ak0 = __builtin_amdgcn_mfma_f32_16x16x32_f16(fk0, xf.v, ak0, 0, 0, 0);
        ak1 = __builtin_amdgcn_mfma_f32_16x16x32_f16(fk1, xf.v, ak1, 0, 0, 0);
        av0 = __builtin_amdgcn_mfma_f32_16x16x32_f16(fv0, xf.v, av0, 0, 0, 0);
        av1 = __builtin_amdgcn_mfma_f32_16x16x32_f16(fv1, xf.v, av1, 0, 0, 0);
    }

    // C-layout: col n = l15, row d = 4g+r (dt0) / 16+4g+r (dt1).
    {
        f16x4 h0, h1;
        #pragma unroll
        for (int r = 0; r < 4; ++r) { h0[r] = (f16)aq0[r]; h1[r] = (f16)aq1[r]; }
        f16* qp = Q + ((size_t)b * N_ + n) * D_ + 4 * g;
        *(f16x4*)qp = h0; *(f16x4*)(qp + 16) = h1;
    }
    {
        f16x4 h0, h1;
        #pragma unroll
        for (int r = 0; r < 4; ++r) { h0[r] = (f16)ak0[r]; h1[r] = (f16)ak1[r]; }
        f16* kp = K + ((size_t)b * N_ + n) * D_ + 4 * g;
        *(f16x4*)kp = h0; *(f16x4*)(kp + 16) = h1;
    }
    // V transposed [b][d][cidx(n)] with per-32-key window column permutation
    {
        const int p = n & 31;
        const int cidx = (n & ~31) + 8 * ((p >> 2) & 3) + 4 * ((p >> 4) & 1) + (p & 3);
        f16* vb = Vt + ((size_t)b * D_ + 4 * g) * N_ + cidx;
        #pragma unroll
        for (int r = 0; r < 4; ++r) {
            vb[(size_t)r * N_]        = (f16)av0[r];
            vb[(size_t)(16 + r) * N_] = (f16)av1[r];
        }
    }
}

// ---- kernel 2: fp16 MFMA flash attention (exp2 domain, q-split) ---------
// grid (b=8, kc=kcnt, qt=64), 256 thr = 4 waves; wave owns 16 q-rows.
// 2048 blocks -> ~8 blocks/CU (grid was the occupancy limiter at 32 q/wave).
// (256,4) kept from the known-good config; per-wave state is now smaller.
__global__ __launch_bounds__(256, 4) void flash_kernel(
    const f16* __restrict__ Qh, const f16* __restrict__ Kh,
    const f16* __restrict__ Vth, float* __restrict__ Opart,
    float* __restrict__ Ml, int kcnt, int kch)
{
    const int lane = threadIdx.x & 63;
    const int wid = threadIdx.x >> 6;
    const int b = blockIdx.x, kc = blockIdx.y, qt = blockIdx.z;
    const int q0 = qt * 64 + wid * 16;
    const int l15 = lane & 15, g = lane >> 4;

    const f16* qp = Qh + ((size_t)b * N_ + q0 + l15) * D_ + g * 8;
    const f16x8 qf0 = *(const f16x8*)qp;

    const f16* kp = Kh + ((size_t)b * N_ + (size_t)kc * kch + l15) * D_ + g * 8;
    const f16* vp = Vth + ((size_t)b * D_ + l15) * N_ + (size_t)kc * kch + g * 8;

    f32x4 O00 = {0.f, 0.f, 0.f, 0.f};
    f32x4 O01 = O00;
    float m0 = -3e38f, l0 = 0.f;
    const int NW = kch >> 5;

    f16x8 kf0 = *(const f16x8*)kp;
    f16x8 kf1 = *(const f16x8*)(kp + (size_t)16 * D_);
    f16x8 vf0 = *(const f16x8*)vp;
    f16x8 vf1 = *(const f16x8*)(vp + (size_t)16 * N_);

    for (int w = 0; w < NW; ++w) {
        const int wn = (w + 1 < NW) ? (w + 1) : w;
        const f16* kpn = kp + (size_t)wn * 32 * D_;
        const f16* vpn = vp + (size_t)wn * 32;
        const f16x8 kn0 = *(const f16x8*)kpn;
        const f16x8 kn1 = *(const f16x8*)(kpn + (size_t)16 * D_);
        const f16x8 vn0 = *(const f16x8*)vpn;
        const f16x8 vn1 = *(const f16x8*)(vpn + (size_t)16 * N_);

        const f32x4 z = {0.f, 0.f, 0.f, 0.f};
        __builtin_amdgcn_s_setprio(1);
        f32x4 s00 = __builtin_amdgcn_mfma_f32_16x16x32_f16(kf0, qf0, z, 0, 0, 0);
        f32x4 s01 = __builtin_amdgcn_mfma_f32_16x16x32_f16(kf1, qf0, z, 0, 0, 0);
        __builtin_amdgcn_s_setprio(0);

        union { f16x8 v; h16x2 h[4]; } pb0;
        {
            float mx = fmaxf(fmaxf(fmaxf(s00[0], s00[1]), fmaxf(s00[2], s00[3])),
                             fmaxf(fmaxf(s01[0], s01[1]), fmaxf(s01[2], s01[3])));
            mx = fmaxf(mx, __shfl_xor(mx, 16));
            mx = fmaxf(mx, __shfl_xor(mx, 32));
            if (__any(mx > m0 + 10.f)) {         // defer-max (T13), log2 units
                const float nm = fmaxf(m0, mx);
                const float f = fexp2(m0 - nm);
                m0 = nm; l0 *= f;
                #pragma unroll
                for (int r = 0; r < 4; ++r) { O00[r] *= f; O01[r] *= f; }
            }
            const float p0 = fexp2(s00[0] - m0), p1 = fexp2(s00[1] - m0);
            const float p2 = fexp2(s00[2] - m0), p3 = fexp2(s00[3] - m0);
            const float p4 = fexp2(s01[0] - m0), p5 = fexp2(s01[1] - m0);
            const float p6 = fexp2(s01[2] - m0), p7 = fexp2(s01[3] - m0);
            l0 += ((p0 + p1) + (p2 + p3)) + ((p4 + p5) + (p6 + p7));
            pb0.h[0] = __builtin_amdgcn_cvt_pkrtz(p0, p1);
            pb0.h[1] = __builtin_amdgcn_cvt_pkrtz(p2, p3);
            pb0.h[2] = __builtin_amdgcn_cvt_pkrtz(p4, p5);
            pb0.h[3] = __builtin_amdgcn_cvt_pkrtz(p6, p7);
        }

        __builtin_amdgcn_s_setprio(1);
        O00 = __builtin_amdgcn_mfma_f32_16x16x32_f16(vf0, pb0.v, O00, 0, 0, 0);
        O01 = __builtin_amdgcn_mfma_f32_16x16x32_f16(vf1, pb0.v, O01, 0, 0, 0);
        __builtin_amdgcn_s_setprio(0);

        kf0 = kn0; kf1 = kn1; vf0 = vn0; vf1 = vn1;
    }

    l0 += __shfl_xor(l0, 16); l0 += __shfl_xor(l0, 32);

    // Opart [b][kc][n][d]: lane stores float4 at (n = q0+l15, d = dt*16+4g)
    float* ob = Opart + ((size_t)(b * kcnt + kc) * N_ + q0) * D_;
    *(f32x4*)(ob + (size_t)l15 * D_ + 4 * g) = O00;               // dt=0
    *(f32x4*)(ob + (size_t)l15 * D_ + 16 + 4 * g) = O01;          // dt=1
    if (lane < 16) {
        float2* mp = (float2*)(Ml + ((size_t)(b * kcnt + kc) * N_ + q0 + l15) * 2);
        mp[0] = make_float2(m0, l0);
    }
}

// ---- kernel 3: merge partials + MFMA Wo projection + residual (R9) ------
__global__ __launch_bounds__(256) void merge2_kernel(
    const float* __restrict__ Opart, const float* __restrict__ Ml,
    const f16* __restrict__ woh, const float* __restrict__ x,
    float* __restrict__ out, int kcnt)
{
    const int lane = threadIdx.x & 63, wid = threadIdx.x >> 6;
    const int b = blockIdx.y;
    const int n0 = blockIdx.x * 64 + wid * 16;
    const int l15 = lane & 15, g = lane >> 4;
    const int n = n0 + l15;

    float mstar = -3e38f;
    for (int kc = 0; kc < kcnt; ++kc)
        mstar = fmaxf(mstar, Ml[(((size_t)b * kcnt + kc) * N_ + n) * 2]);

    float acc[8];
    #pragma unroll
    for (int j = 0; j < 8; ++j) acc[j] = 0.f;
    float lstar = 0.f;
    for (int kc = 0; kc < kcnt; ++kc) {
        const float2 ml = *(const float2*)(Ml + (((size_t)b * kcnt + kc) * N_ + n) * 2);
        const float wgt = fexp2(ml.x - mstar);
        lstar += wgt * ml.y;
        const float* op = Opart + ((size_t)(b * kcnt + kc) * N_ + n) * D_ + g * 8;
        const f32x4 o0 = *(const f32x4*)op;
        const f32x4 o1 = *(const f32x4*)(op + 4);
        #pragma unroll
        for (int j = 0; j < 4; ++j) { acc[j] += wgt * o0[j]; acc[4 + j] += wgt * o1[j]; }
    }
    const float inv = 1.0f / lstar;
    union { f16x8 v; h16x2 h[4]; } oc;
    #pragma unroll
    for (int j = 0; j < 4; ++j)
        oc.h[j] = __builtin_amdgcn_cvt_pkrtz(acc[2 * j] * inv, acc[2 * j + 1] * inv);

    const float* xb = x + (size_t)b * C_ * N_;
    float* ob = out + (size_t)b * C_ * N_;
    const f32x4 z = {0.f, 0.f, 0.f, 0.f};
    #pragma unroll
    for (int ct = 0; ct < 16; ++ct) {
        const f16x8 wf = *(const f16x8*)(woh + (ct * 16 + l15) * 32 + g * 8);
        const f32x4 o = __builtin_amdgcn_mfma_f32_16x16x32_f16(wf, oc.v, z, 0, 0, 0);
        #pragma unroll
        for (int r = 0; r < 4; ++r) {
            const size_t off = (size_t)(ct * 16 + 4 * g + r) * N_ + n;
            ob[off] = o[r] + xb[off];   // gamma already folded into woh
        }
    }
}

extern "C" void kernel_launch(void* const* d_in, const int* in_sizes, int n_in,
                              void* d_out, int out_size, void* d_ws, size_t ws_size,
                              hipStream_t stream) {
    const float* x  = (const float*)d_in[0];
    const float* wq = (const float*)d_in[1];
    const float* wk = (const float*)d_in[2];
    const float* wv = (const float*)d_in[3];
    const float* wo = (const float*)d_in[4];
    const float* gm = (const float*)d_in[5];
    float* out = (float*)d_out;

    int kcnt = 4;
    while (kcnt > 1) {
        const size_t need = 65536                               // fp16 weights
                          + 3 * (size_t)B_ * N_ * D_ * 2        // Q,K,Vt fp16
                          + (size_t)kcnt * B_ * N_ * D_ * 4     // Opart
                          + (size_t)kcnt * B_ * N_ * 2 * 4;     // Ml
        if (need <= ws_size) break;
        kcnt >>= 1;
    }
    const int kch = N_ / kcnt;

    f16* whq = (f16*)d_ws;
    f16* whk = whq + 8192;
    f16* whv = whk + 8192;
    f16* woh = whv + 8192;
    f16* Qb  = woh + 8192;
    f16* Kb  = Qb + (size_t)B_ * N_ * D_;
    f16* Vtb = Kb + (size_t)B_ * N_ * D_;
    float* Opart = (float*)(Vtb + (size_t)B_ * N_ * D_);
    float* Mlb   = Opart + (size_t)kcnt * B_ * N_ * D_;

    prep_kernel<<<32, 256, 0, stream>>>(wq, wk, wv, wo, gm, whq, whk, whv, woh);
    qkv2_kernel<<<dim3(64, B_), 256, 0, stream>>>(x, whq, whk, whv, Qb, Kb, Vtb);
    flash_kernel<<<dim3(B_, kcnt, N_ / 64), 256, 0, stream>>>(Qb, Kb, Vtb, Opart, Mlb,
                                                              kcnt, kch);
    merge2_kernel<<<dim3(64, B_), 256, 0, stream>>>(Opart, Mlb, woh, x, out, kcnt);
}

// Round 12
// 166.776 us; speedup vs baseline: 1.3545x; 1.3545x over previous
//
#include <hip/hip_runtime.h>
#include <hip/hip_bf16.h>
#include <hip/hip_fp16.h>

// Self-attention B=8,C=256,H=W=64 -> N=4096, D=32 — all-MFMA pipeline.
// prep -> qkv2 (MFMA, LDS-staged x; R9-exact) -> flash (f16 MFMA, 64 q/wave,
// kcnt=4) -> merge2 (MFMA wo-proj; R9-exact).
// R11 evidence: flash time ∝ loads/MFMA ratio (16q=120.8us, 32q=55.6us)
// -> this round 64 q/wave (2x MFMA per K/V byte). Single change vs R11.

typedef _Float16 f16;
typedef f16 f16x8 __attribute__((ext_vector_type(8)));
typedef f16 f16x4 __attribute__((ext_vector_type(4)));
typedef __fp16 h16x2 __attribute__((ext_vector_type(2)));   // cvt_pkrtz return type
typedef float f32x4 __attribute__((ext_vector_type(4)));

#define B_ 8
#define C_ 256
#define N_ 4096
#define D_ 32
#define LOG2E 1.44269504088896f

// native v_exp_f32 computes 2^x; non-volatile so the scheduler can interleave
__device__ __forceinline__ float fexp2(float x) {
    float r;
    asm("v_exp_f32 %0, %1" : "=v"(r) : "v"(x));
    return r;
}

// ---- kernel 0: weight prep (fp32 -> fp16, scale folds) ------------------
__global__ __launch_bounds__(256) void prep_kernel(
    const float* __restrict__ wq, const float* __restrict__ wk,
    const float* __restrict__ wv, const float* __restrict__ wo,
    const float* __restrict__ gamma,
    f16* __restrict__ whq, f16* __restrict__ whk,
    f16* __restrict__ whv, f16* __restrict__ woh)
{
    const int i = blockIdx.x * 256 + threadIdx.x;
    whq[i] = (f16)(wq[i] * LOG2E);      // exp2-domain softmax: s' = s*log2e
    whk[i] = (f16)wk[i];
    whv[i] = (f16)wv[i];
    woh[i] = (f16)(wo[i] * gamma[0]);   // fold gamma into output projection
}

// ---- kernel 1: QKV projection via MFMA, x staged in LDS (R9-exact) ------
__global__ __launch_bounds__(256) void qkv2_kernel(
    const float* __restrict__ x, const f16* __restrict__ whq,
    const f16* __restrict__ whk, const f16* __restrict__ whv,
    f16* __restrict__ Q, f16* __restrict__ K, f16* __restrict__ Vt)
{
    __shared__ f16 xl[256][66];
    const int tid = threadIdx.x;
    const int lane = tid & 63, wid = tid >> 6;
    const int b = blockIdx.y;
    const int n0 = blockIdx.x * 64;
    const int l15 = lane & 15, g = lane >> 4;
    const int nl = wid * 16 + l15;          // n-local in [0,64)
    const int n = n0 + nl;

    // stage: coalesced float4 reads of x[c][n0..n0+63], fp16-convert to LDS
    {
        const float* xb = x + (size_t)b * C_ * N_ + n0;
        const int cb = tid >> 4, ncb = (tid & 15) * 4;
        #pragma unroll
        for (int i = 0; i < 16; ++i) {
            const int c = i * 16 + cb;
            const float4 xv = *(const float4*)(xb + (size_t)c * N_ + ncb);
            *(h16x2*)&xl[c][ncb]     = __builtin_amdgcn_cvt_pkrtz(xv.x, xv.y);
            *(h16x2*)&xl[c][ncb + 2] = __builtin_amdgcn_cvt_pkrtz(xv.z, xv.w);
        }
    }
    __syncthreads();

    f32x4 aq0 = {0.f, 0.f, 0.f, 0.f};
    f32x4 aq1 = aq0, ak0 = aq0, ak1 = aq0, av0 = aq0, av1 = aq0;

    #pragma unroll
    for (int ks = 0; ks < 8; ++ks) {
        const int c0 = ks * 32 + g * 8;
        union { f16x8 v; f16 e[8]; } xf;
        #pragma unroll
        for (int j = 0; j < 8; ++j) xf.e[j] = xl[c0 + j][nl];

        const int woff = l15 * 256 + c0;         // A-frag row d=l15 (+16 for dt1)
        const f16x8 fq0 = *(const f16x8*)(whq + woff);
        const f16x8 fq1 = *(const f16x8*)(whq + woff + 16 * 256);
        const f16x8 fk0 = *(const f16x8*)(whk + woff);
        const f16x8 fk1 = *(const f16x8*)(whk + woff + 16 * 256);
        const f16x8 fv0 = *(const f16x8*)(whv + woff);
        const f16x8 fv1 = *(const f16x8*)(whv + woff + 16 * 256);

        aq0 = __builtin_amdgcn_mfma_f32_16x16x32_f16(fq0, xf.v, aq0, 0, 0, 0);
        aq1 = __builtin_amdgcn_mfma_f32_16x16x32_f16(fq1, xf.v, aq1, 0, 0, 0);
        ak0 = __builtin_amdgcn_mfma_f32_16x16x32_f16(fk0, xf.v, ak0, 0, 0, 0);
        ak1 = __builtin_amdgcn_mfma_f32_16x16x32_f16(fk1, xf.v, ak1, 0, 0, 0);
        av0 = __builtin_amdgcn_mfma_f32_16x16x32_f16(fv0, xf.v, av0, 0, 0, 0);
        av1 = __builtin_amdgcn_mfma_f32_16x16x32_f16(fv1, xf.v, av1, 0, 0, 0);
    }

    // C-layout: col n = l15, row d = 4g+r (dt0) / 16+4g+r (dt1).
    {
        f16x4 h0, h1;
        #pragma unroll
        for (int r = 0; r < 4; ++r) { h0[r] = (f16)aq0[r]; h1[r] = (f16)aq1[r]; }
        f16* qp = Q + ((size_t)b * N_ + n) * D_ + 4 * g;
        *(f16x4*)qp = h0; *(f16x4*)(qp + 16) = h1;
    }
    {
        f16x4 h0, h1;
        #pragma unroll
        for (int r = 0; r < 4; ++r) { h0[r] = (f16)ak0[r]; h1[r] = (f16)ak1[r]; }
        f16* kp = K + ((size_t)b * N_ + n) * D_ + 4 * g;
        *(f16x4*)kp = h0; *(f16x4*)(kp + 16) = h1;
    }
    // V transposed [b][d][cidx(n)] with per-32-key window column permutation
    {
        const int p = n & 31;
        const int cidx = (n & ~31) + 8 * ((p >> 2) & 3) + 4 * ((p >> 4) & 1) + (p & 3);
        f16* vb = Vt + ((size_t)b * D_ + 4 * g) * N_ + cidx;
        #pragma unroll
        for (int r = 0; r < 4; ++r) {
            vb[(size_t)r * N_]        = (f16)av0[r];
            vb[(size_t)(16 + r) * N_] = (f16)av1[r];
        }
    }
}

// ---- kernel 2: fp16 MFMA flash attention (exp2 domain, 64 q/wave) -------
// grid (b=8, kc=kcnt, qt=16), 256 thr = 4 waves; wave owns 64 q-rows.
// 512 blocks = 2 blocks/CU; (256,2) caps VGPR at 256 — prefetch stays in
// registers (R5 lesson). ILP: 16 MFMA + 4 indep softmax chains per window.
__global__ __launch_bounds__(256, 2) void flash_kernel(
    const f16* __restrict__ Qh, const f16* __restrict__ Kh,
    const f16* __restrict__ Vth, float* __restrict__ Opart,
    float* __restrict__ Ml, int kcnt, int kch)
{
    const int lane = threadIdx.x & 63;
    const int wid = threadIdx.x >> 6;
    const int b = blockIdx.x, kc = blockIdx.y, qt = blockIdx.z;
    const int q0 = qt * 256 + wid * 64;
    const int l15 = lane & 15, g = lane >> 4;

    const f16* qp = Qh + ((size_t)b * N_ + q0 + l15) * D_ + g * 8;
    f16x8 qf[4];
    #pragma unroll
    for (int s = 0; s < 4; ++s) qf[s] = *(const f16x8*)(qp + (size_t)(s * 16) * D_);

    const f16* kp = Kh + ((size_t)b * N_ + (size_t)kc * kch + l15) * D_ + g * 8;
    const f16* vp = Vth + ((size_t)b * D_ + l15) * N_ + (size_t)kc * kch + g * 8;

    f32x4 O[8];
    #pragma unroll
    for (int j = 0; j < 8; ++j) O[j] = (f32x4){0.f, 0.f, 0.f, 0.f};
    float m[4], l[4];
    #pragma unroll
    for (int s = 0; s < 4; ++s) { m[s] = -3e38f; l[s] = 0.f; }
    const int NW = kch >> 5;

    f16x8 kf0 = *(const f16x8*)kp;
    f16x8 kf1 = *(const f16x8*)(kp + (size_t)16 * D_);
    f16x8 vf0 = *(const f16x8*)vp;
    f16x8 vf1 = *(const f16x8*)(vp + (size_t)16 * N_);

    for (int w = 0; w < NW; ++w) {
        const int wn = (w + 1 < NW) ? (w + 1) : w;
        const f16* kpn = kp + (size_t)wn * 32 * D_;
        const f16* vpn = vp + (size_t)wn * 32;
        const f16x8 kn0 = *(const f16x8*)kpn;
        const f16x8 kn1 = *(const f16x8*)(kpn + (size_t)16 * D_);
        const f16x8 vn0 = *(const f16x8*)vpn;
        const f16x8 vn1 = *(const f16x8*)(vpn + (size_t)16 * N_);

        const f32x4 z = {0.f, 0.f, 0.f, 0.f};
        union { f16x8 v; h16x2 h[4]; } pb[4];

        // per-subtile QK^T + softmax (keeps S-tile register lifetime short)
        #pragma unroll
        for (int s = 0; s < 4; ++s) {
            __builtin_amdgcn_s_setprio(1);
            const f32x4 sa = __builtin_amdgcn_mfma_f32_16x16x32_f16(kf0, qf[s], z, 0, 0, 0);
            const f32x4 sb = __builtin_amdgcn_mfma_f32_16x16x32_f16(kf1, qf[s], z, 0, 0, 0);
            __builtin_amdgcn_s_setprio(0);

            float mx = fmaxf(fmaxf(fmaxf(sa[0], sa[1]), fmaxf(sa[2], sa[3])),
                             fmaxf(fmaxf(sb[0], sb[1]), fmaxf(sb[2], sb[3])));
            mx = fmaxf(mx, __shfl_xor(mx, 16));
            mx = fmaxf(mx, __shfl_xor(mx, 32));
            if (__any(mx > m[s] + 10.f)) {       // defer-max (T13), log2 units
                const float nm = fmaxf(m[s], mx);
                const float f = fexp2(m[s] - nm);
                m[s] = nm; l[s] *= f;
                #pragma unroll
                for (int r = 0; r < 4; ++r) { O[2 * s][r] *= f; O[2 * s + 1][r] *= f; }
            }
            const float p0 = fexp2(sa[0] - m[s]), p1 = fexp2(sa[1] - m[s]);
            const float p2 = fexp2(sa[2] - m[s]), p3 = fexp2(sa[3] - m[s]);
            const float p4 = fexp2(sb[0] - m[s]), p5 = fexp2(sb[1] - m[s]);
            const float p6 = fexp2(sb[2] - m[s]), p7 = fexp2(sb[3] - m[s]);
            l[s] += ((p0 + p1) + (p2 + p3)) + ((p4 + p5) + (p6 + p7));
            pb[s].h[0] = __builtin_amdgcn_cvt_pkrtz(p0, p1);
            pb[s].h[1] = __builtin_amdgcn_cvt_pkrtz(p2, p3);
            pb[s].h[2] = __builtin_amdgcn_cvt_pkrtz(p4, p5);
            pb[s].h[3] = __builtin_amdgcn_cvt_pkrtz(p6, p7);
        }

        // PV: O^T += V^T(dt) . P(s)  (V columns pre-permuted to match slots)
        __builtin_amdgcn_s_setprio(1);
        #pragma unroll
        for (int s = 0; s < 4; ++s) {
            O[2 * s]     = __builtin_amdgcn_mfma_f32_16x16x32_f16(vf0, pb[s].v, O[2 * s], 0, 0, 0);
            O[2 * s + 1] = __builtin_amdgcn_mfma_f32_16x16x32_f16(vf1, pb[s].v, O[2 * s + 1], 0, 0, 0);
        }
        __builtin_amdgcn_s_setprio(0);

        kf0 = kn0; kf1 = kn1; vf0 = vn0; vf1 = vn1;
    }

    #pragma unroll
    for (int s = 0; s < 4; ++s) {
        l[s] += __shfl_xor(l[s], 16);
        l[s] += __shfl_xor(l[s], 32);
    }

    // Opart [b][kc][n][d]: lane stores float4 at (n = q0+s*16+l15, d = dt*16+4g)
    float* ob = Opart + ((size_t)(b * kcnt + kc) * N_ + q0) * D_;
    #pragma unroll
    for (int s = 0; s < 4; ++s) {
        *(f32x4*)(ob + (size_t)(s * 16 + l15) * D_ + 4 * g)      = O[2 * s];
        *(f32x4*)(ob + (size_t)(s * 16 + l15) * D_ + 16 + 4 * g) = O[2 * s + 1];
    }
    if (lane < 16) {
        #pragma unroll
        for (int s = 0; s < 4; ++s) {
            float2* mp = (float2*)(Ml + ((size_t)(b * kcnt + kc) * N_ + q0 + s * 16 + l15) * 2);
            mp[0] = make_float2(m[s], l[s]);
        }
    }
}

// ---- kernel 3: merge partials + MFMA Wo projection + residual (R9) ------
__global__ __launch_bounds__(256) void merge2_kernel(
    const float* __restrict__ Opart, const float* __restrict__ Ml,
    const f16* __restrict__ woh, const float* __restrict__ x,
    float* __restrict__ out, int kcnt)
{
    const int lane = threadIdx.x & 63, wid = threadIdx.x >> 6;
    const int b = blockIdx.y;
    const int n0 = blockIdx.x * 64 + wid * 16;
    const int l15 = lane & 15, g = lane >> 4;
    const int n = n0 + l15;

    float mstar = -3e38f;
    for (int kc = 0; kc < kcnt; ++kc)
        mstar = fmaxf(mstar, Ml[(((size_t)b * kcnt + kc) * N_ + n) * 2]);

    float acc[8];
    #pragma unroll
    for (int j = 0; j < 8; ++j) acc[j] = 0.f;
    float lstar = 0.f;
    for (int kc = 0; kc < kcnt; ++kc) {
        const float2 ml = *(const float2*)(Ml + (((size_t)b * kcnt + kc) * N_ + n) * 2);
        const float wgt = fexp2(ml.x - mstar);
        lstar += wgt * ml.y;
        const float* op = Opart + ((size_t)(b * kcnt + kc) * N_ + n) * D_ + g * 8;
        const f32x4 o0 = *(const f32x4*)op;
        const f32x4 o1 = *(const f32x4*)(op + 4);
        #pragma unroll
        for (int j = 0; j < 4; ++j) { acc[j] += wgt * o0[j]; acc[4 + j] += wgt * o1[j]; }
    }
    const float inv = 1.0f / lstar;
    union { f16x8 v; h16x2 h[4]; } oc;
    #pragma unroll
    for (int j = 0; j < 4; ++j)
        oc.h[j] = __builtin_amdgcn_cvt_pkrtz(acc[2 * j] * inv, acc[2 * j + 1] * inv);

    const float* xb = x + (size_t)b * C_ * N_;
    float* ob = out + (size_t)b * C_ * N_;
    const f32x4 z = {0.f, 0.f, 0.f, 0.f};
    #pragma unroll
    for (int ct = 0; ct < 16; ++ct) {
        const f16x8 wf = *(const f16x8*)(woh + (ct * 16 + l15) * 32 + g * 8);
        const f32x4 o = __builtin_amdgcn_mfma_f32_16x16x32_f16(wf, oc.v, z, 0, 0, 0);
        #pragma unroll
        for (int r = 0; r < 4; ++r) {
            const size_t off = (size_t)(ct * 16 + 4 * g + r) * N_ + n;
            ob[off] = o[r] + xb[off];   // gamma already folded into woh
        }
    }
}

extern "C" void kernel_launch(void* const* d_in, const int* in_sizes, int n_in,
                              void* d_out, int out_size, void* d_ws, size_t ws_size,
                              hipStream_t stream) {
    const float* x  = (const float*)d_in[0];
    const float* wq = (const float*)d_in[1];
    const float* wk = (const float*)d_in[2];
    const float* wv = (const float*)d_in[3];
    const float* wo = (const float*)d_in[4];
    const float* gm = (const float*)d_in[5];
    float* out = (float*)d_out;

    int kcnt = 4;
    while (kcnt > 1) {
        const size_t need = 65536                               // fp16 weights
                          + 3 * (size_t)B_ * N_ * D_ * 2        // Q,K,Vt fp16
                          + (size_t)kcnt * B_ * N_ * D_ * 4     // Opart
                          + (size_t)kcnt * B_ * N_ * 2 * 4;     // Ml
        if (need <= ws_size) break;
        kcnt >>= 1;
    }
    const int kch = N_ / kcnt;

    f16* whq = (f16*)d_ws;
    f16* whk = whq + 8192;
    f16* whv = whk + 8192;
    f16* woh = whv + 8192;
    f16* Qb  = woh + 8192;
    f16* Kb  = Qb + (size_t)B_ * N_ * D_;
    f16* Vtb = Kb + (size_t)B_ * N_ * D_;
    float* Opart = (float*)(Vtb + (size_t)B_ * N_ * D_);
    float* Mlb   = Opart + (size_t)kcnt * B_ * N_ * D_;

    prep_kernel<<<32, 256, 0, stream>>>(wq, wk, wv, wo, gm, whq, whk, whv, woh);
    qkv2_kernel<<<dim3(64, B_), 256, 0, stream>>>(x, whq, whk, whv, Qb, Kb, Vtb);
    flash_kernel<<<dim3(B_, kcnt, N_ / 256), 256, 0, stream>>>(Qb, Kb, Vtb, Opart, Mlb,
                                                               kcnt, kch);
    merge2_kernel<<<dim3(64, B_), 256, 0, stream>>>(Opart, Mlb, woh, x, out, kcnt);
}